// Round 8
// baseline (830.678 us; speedup 1.0000x reference)
//
#include <hip/hip_runtime.h>
#include <hip/hip_cooperative_groups.h>

namespace cg = cooperative_groups;

typedef __bf16 bf16;
typedef __bf16 bf16x8 __attribute__((ext_vector_type(8)));
typedef __bf16 bf16x4 __attribute__((ext_vector_type(4)));
typedef float f32x4 __attribute__((ext_vector_type(4)));
typedef unsigned long long u64;

#define MFMA16(a, b, c) __builtin_amdgcn_mfma_f32_16x16x32_bf16(a, b, c, 0, 0, 0)

// Async global->LDS, 16 B/lane; LDS dest = wave-uniform base + lane*16.
__device__ __forceinline__ void gl_lds16(const void* g, void* l) {
  __builtin_amdgcn_global_load_lds(
      (const __attribute__((address_space(1))) unsigned int*)g,
      (__attribute__((address_space(3))) unsigned int*)l, 16, 0, 0);
}

// ---------------------------------------------------------------------------
// Phase bodies (shared between the cooperative mega-kernel and the 4-kernel
// fallback). All are the round-3/6 proven implementations, with LDS passed
// as a raw char* (mega uses one 48 KB arena for all phases).
// ---------------------------------------------------------------------------

// ---- prep unit u in [0,5376): 0..1023 weight transpose; 1024..1279 mask
// pack; 1280..3327 context downcast; 3328..5375 x downcast.
__device__ __forceinline__ void prep_unit(
    char* smraw, int u, int tid, const float* __restrict__ Wq,
    const float* __restrict__ Wkv, const float* __restrict__ Wp,
    const int* __restrict__ mask, const float* __restrict__ context,
    const float* __restrict__ x, bf16* __restrict__ BqkvT,
    bf16* __restrict__ WpT, u64* __restrict__ maskbits, bf16* __restrict__ cb,
    bf16* __restrict__ xb) {
  if (u >= 3328) {  // ---- x downcast
    const size_t i = ((size_t)(u - 3328) * 256 + tid) * 8;
    f32x4 a0 = *(const f32x4*)(x + i);
    f32x4 a1 = *(const f32x4*)(x + i + 4);
    bf16x8 t;
#pragma unroll
    for (int j = 0; j < 4; ++j) { t[j] = (bf16)a0[j]; t[4 + j] = (bf16)a1[j]; }
    *(bf16x8*)(xb + i) = t;
    return;
  }
  if (u >= 1280) {  // ---- context downcast
    const size_t i = ((size_t)(u - 1280) * 256 + tid) * 8;
    f32x4 a0 = *(const f32x4*)(context + i);
    f32x4 a1 = *(const f32x4*)(context + i + 4);
    bf16x8 t;
#pragma unroll
    for (int j = 0; j < 4; ++j) { t[j] = (bf16)a0[j]; t[4 + j] = (bf16)a1[j]; }
    *(bf16x8*)(cb + i) = t;
    return;
  }
  if (u >= 1024) {  // ---- mask pack
    const int idx = (u - 1024) * 256 + tid;
    const int4* p = (const int4*)(mask + (size_t)idx * 64);
    u64 v = 0;
#pragma unroll
    for (int i = 0; i < 16; ++i) {
      int4 m = p[i];
      v |= (u64)(m.x != 0) << (4 * i);
      v |= (u64)(m.y != 0) << (4 * i + 1);
      v |= (u64)(m.z != 0) << (4 * i + 2);
      v |= (u64)(m.w != 0) << (4 * i + 3);
    }
    maskbits[idx] = v;
    return;
  }
  // ---- weight transpose tile (uses LDS; syncs internally; trailing sync
  // protects the arena for the next grid-stride unit).
  auto T = reinterpret_cast<bf16(*)[72]>(smraw);  // [64][72]
  const int ct = u >> 4, rt = u & 15;
  const float* src;
  bf16* dst;
  int C, c0, drow0;
  if (ct < 16) {
    src = Wq; C = 1024; c0 = ct * 64; dst = BqkvT; drow0 = c0;
  } else if (ct < 48) {
    src = Wkv; C = 2048; c0 = (ct - 16) * 64; dst = BqkvT; drow0 = 1024 + c0;
  } else {
    src = Wp; C = 1024; c0 = (ct - 48) * 64; dst = WpT; drow0 = c0;
  }
  const int r0 = rt * 64;
#pragma unroll
  for (int i = 0; i < 2; ++i) {
    int c = i * 256 + tid;
    int row = c >> 3, col = (c & 7) * 8;
    const float* sp = &src[(size_t)(r0 + row) * C + c0 + col];
    f32x4 a0 = *(const f32x4*)sp;
    f32x4 a1 = *(const f32x4*)(sp + 4);
    bf16x8 t;
#pragma unroll
    for (int j = 0; j < 4; ++j) { t[j] = (bf16)a0[j]; t[4 + j] = (bf16)a1[j]; }
    *(bf16x8*)&T[row][col] = t;
  }
  __syncthreads();
#pragma unroll
  for (int i = 0; i < 2; ++i) {
    int c = i * 256 + tid;
    int orow = c >> 3, ocol = (c & 7) * 8;
    bf16x8 v;
#pragma unroll
    for (int j = 0; j < 8; ++j) v[j] = T[ocol + j][orow];
    *(bf16x8*)&dst[(size_t)(drow0 + orow) * 1024 + r0 + ocol] = v;
  }
  __syncthreads();  // WAR protection for the next unit reusing T
}

// ---- db2 GEMM body (round-2/3 proven): 128xBN, BK=32, dbuf, one
// __syncthreads per K-step, next tile's global_load_lds in flight across
// current MFMAs, 16B-granule XOR swizzle (0 conflicts).
template <int EPI, int BN>
__device__ __forceinline__ void gemm_body(
    char* smraw, int m0, int n0, const bf16* __restrict__ A0,
    const bf16* __restrict__ A1, const bf16* __restrict__ Bt,
    const float* __restrict__ bias0, const float* __restrict__ bias1,
    bf16* __restrict__ oq, bf16* __restrict__ ok, bf16* __restrict__ ovt,
    float* __restrict__ outf) {
  constexpr int NJ = BN / 32;
  auto As = reinterpret_cast<bf16(*)[128][32]>(smraw);           // [2][128][32]
  auto Bs = reinterpret_cast<bf16(*)[BN][32]>(smraw + 16384);    // [2][BN][32]
  const int tid = threadIdx.x;
  const int lane = tid & 63;
  const int w = tid >> 6;
  const int wm = (w >> 1) * 64;
  const int wn = (w & 1) * (BN / 2);
  const int l15 = lane & 15, l4 = lane >> 4;
  const int lrow = lane >> 2;
  const int lcg = (lane & 3) ^ ((lrow >> 1) & 3);
  const int rdc = (l4 ^ ((l15 >> 1) & 3)) * 8;

  const bf16* Asrc = (EPI == 1) ? ((n0 < 1024) ? A0 : A1) : A0;

  f32x4 acc[4][NJ] = {};

#define STAGE(kk, buf)                                                        \
  {                                                                           \
    _Pragma("unroll") for (int it = 0; it < 2; ++it) {                        \
      const int r = w * 32 + it * 16;                                         \
      gl_lds16(&Asrc[(size_t)(m0 + r + lrow) * 1024 + (kk) + lcg * 8],        \
               &As[buf][r][0]);                                               \
    }                                                                         \
    _Pragma("unroll") for (int it = 0; it < BN / 64; ++it) {                  \
      const int r = w * (BN / 4) + it * 16;                                   \
      gl_lds16(&Bt[(size_t)(n0 + r + lrow) * 1024 + (kk) + lcg * 8],          \
               &Bs[buf][r][0]);                                               \
    }                                                                         \
  }

#define COMPUTE(buf)                                                          \
  {                                                                           \
    bf16x8 af[4], bfr[NJ];                                                    \
    _Pragma("unroll") for (int i = 0; i < 4; ++i) af[i] =                     \
        *(const bf16x8*)&As[buf][wm + i * 16 + l15][rdc];                     \
    _Pragma("unroll") for (int j = 0; j < NJ; ++j) bfr[j] =                   \
        *(const bf16x8*)&Bs[buf][wn + j * 16 + l15][rdc];                     \
    _Pragma("unroll") for (int i = 0; i < 4; ++i)                             \
        _Pragma("unroll") for (int j = 0; j < NJ; ++j) acc[i][j] =            \
            MFMA16(af[i], bfr[j], acc[i][j]);                                 \
  }

  STAGE(0, 0);
  for (int k = 0; k < 32; k += 2) {
    __syncthreads();
    STAGE((k + 1) * 32, 1);
    COMPUTE(0);
    __syncthreads();
    if (k < 30) STAGE((k + 2) * 32, 0);
    COMPUTE(1);
  }
#undef STAGE
#undef COMPUTE

  const float SCALE2 = 0.18033688011112042f;  // 1/sqrt(64) * log2(e)
#pragma unroll
  for (int j = 0; j < NJ; ++j) {
    const int col = n0 + wn + j * 16 + l15;
    float bc;
    if (EPI == 1) bc = (col < 1024) ? bias0[col] : bias1[col - 1024];
    else bc = bias0[col];
#pragma unroll
    for (int i = 0; i < 4; ++i) {
#pragma unroll
      for (int r = 0; r < 4; ++r) {
        const int row = m0 + wm + i * 16 + l4 * 4 + r;
        const float v = acc[i][j][r] + bc;
        if (EPI == 0) {
          outf[(size_t)row * 1024 + col] = v;
        } else {
          const int b = row >> 10, n = row & 1023;
          if (col < 1024) {
            const int h = col >> 6, d = col & 63;
            oq[(((size_t)(b * 16 + h)) * 1024 + n) * 64 + d] =
                (bf16)(v * SCALE2);
          } else {
            const int ckv = col - 1024;
            const int s = ckv >> 10, c2 = ckv & 1023;
            const int h = c2 >> 6, d = c2 & 63;
            if (s == 0)
              ok[(((size_t)(b * 16 + h)) * 1024 + n) * 64 + d] = (bf16)v;
            else
              ovt[(((size_t)(b * 16 + h)) * 64 + d) * 1024 + n] = (bf16)v;
          }
        }
      }
    }
  }
}

// ---- attention v3 body (round-6, worked): 32 q-rows/wave, swapped QK^T,
// K/V frags shared across 2 q-frags, XOR-swizzled gl_lds staging, dbuf.
__device__ __forceinline__ void attn_body(char* smraw, int bh, int ntile,
                                          const bf16* __restrict__ q,
                                          const bf16* __restrict__ k,
                                          const bf16* __restrict__ vT,
                                          const u64* __restrict__ maskbits,
                                          bf16* __restrict__ ao) {
  auto Ks = reinterpret_cast<bf16(*)[64][64]>(smraw);            // [2][64][64]
  auto Vts = reinterpret_cast<bf16(*)[64][64]>(smraw + 16384);   // [2][64][64]
  auto Pw = reinterpret_cast<bf16(*)[32][64]>(smraw + 32768);    // [4][32][64]
  const int b = bh >> 4, h = bh & 15;
  const int tid = threadIdx.x;
  const int lane = tid & 63;
  const int w = tid >> 6;
  const int l15 = lane & 15, l4 = lane >> 4;

  const size_t base = (size_t)bh * 65536;
  const int nrow0 = ntile * 128 + w * 32;

  bf16x8 qf[2][2];
#pragma unroll
  for (int f = 0; f < 2; ++f)
#pragma unroll
    for (int ks = 0; ks < 2; ++ks)
      qf[f][ks] = *(const bf16x8*)&q[base +
                                     (size_t)(nrow0 + f * 16 + l15) * 64 +
                                     ks * 32 + l4 * 8];

  const u64* mb = maskbits + (size_t)(b * 1024 + nrow0 + l15) * 16;

  const int srow = lane >> 3;
  const int sgl = (lane & 7) ^ srow;
  const bf16* kp = &k[base + (size_t)(w * 16 + srow) * 64 + sgl * 8];
  const bf16* vp = &vT[base + (size_t)(w * 16 + srow) * 1024 + sgl * 8];

  const int rc0 = ((0 + l4) ^ (l15 & 7)) * 8;
  const int rc1 = ((4 + l4) ^ (l15 & 7)) * 8;

  f32x4 o[2][4] = {};
  float lsum[2] = {0.0f, 0.0f};

#define STAGEA(mt_, buf_)                                                     \
  {                                                                           \
    _Pragma("unroll") for (int it = 0; it < 2; ++it) {                        \
      gl_lds16(kp + (size_t)((mt_)*64 + it * 8) * 64,                         \
               &Ks[buf_][w * 16 + it * 8][0]);                                \
      gl_lds16(vp + (size_t)(it * 8) * 1024 + (mt_)*64,                       \
               &Vts[buf_][w * 16 + it * 8][0]);                               \
    }                                                                         \
  }

  STAGEA(0, 0);
  for (int mt = 0; mt < 16; ++mt) {
    const int cur = mt & 1;
    __syncthreads();
    if (mt < 15) STAGEA(mt + 1, cur ^ 1);
    const u64 wm0 = mb[mt];
    const u64 wm1 = mb[256 + mt];

    f32x4 s[2][4];
#pragma unroll
    for (int f = 0; f < 2; ++f)
#pragma unroll
      for (int sub = 0; sub < 4; ++sub)
        s[f][sub] = f32x4{-12.f, -12.f, -12.f, -12.f};
    __builtin_amdgcn_s_setprio(1);
#pragma unroll
    for (int sub = 0; sub < 4; ++sub) {
      bf16x8 kf0 = *(const bf16x8*)&Ks[cur][sub * 16 + l15][rc0];
      bf16x8 kf1 = *(const bf16x8*)&Ks[cur][sub * 16 + l15][rc1];
      s[0][sub] = MFMA16(kf0, qf[0][0], s[0][sub]);
      s[0][sub] = MFMA16(kf1, qf[0][1], s[0][sub]);
      s[1][sub] = MFMA16(kf0, qf[1][0], s[1][sub]);
      s[1][sub] = MFMA16(kf1, qf[1][1], s[1][sub]);
    }
    __builtin_amdgcn_s_setprio(0);

#pragma unroll
    for (int f = 0; f < 2; ++f) {
      const u64 wmt = f ? wm1 : wm0;
#pragma unroll
      for (int sub = 0; sub < 4; ++sub) {
        const int kbit = sub * 16 + l4 * 4;
        float p[4];
#pragma unroll
        for (int r = 0; r < 4; ++r) {
          float e = exp2f(s[f][sub][r]);
          p[r] = ((wmt >> (kbit + r)) & 1) ? e : 0.0f;
        }
        lsum[f] += (p[0] + p[1]) + (p[2] + p[3]);
        bf16x4 pv;
#pragma unroll
        for (int r = 0; r < 4; ++r) pv[r] = (bf16)p[r];
        const int gw = sub * 2 + (l4 >> 1);
        char* pd = (char*)&Pw[w][f * 16 + l15][0] +
                   ((gw ^ (l15 & 7)) * 16 + (l4 & 1) * 8);
        *(bf16x4*)pd = pv;
      }
    }

    bf16x8 af[2][2];
#pragma unroll
    for (int f = 0; f < 2; ++f) {
      af[f][0] = *(const bf16x8*)&Pw[w][f * 16 + l15][rc0];
      af[f][1] = *(const bf16x8*)&Pw[w][f * 16 + l15][rc1];
    }
    __builtin_amdgcn_s_setprio(1);
#pragma unroll
    for (int sub = 0; sub < 4; ++sub) {
      bf16x8 vf0 = *(const bf16x8*)&Vts[cur][sub * 16 + l15][rc0];
      bf16x8 vf1 = *(const bf16x8*)&Vts[cur][sub * 16 + l15][rc1];
      o[0][sub] = MFMA16(af[0][0], vf0, o[0][sub]);
      o[0][sub] = MFMA16(af[0][1], vf1, o[0][sub]);
      o[1][sub] = MFMA16(af[1][0], vf0, o[1][sub]);
      o[1][sub] = MFMA16(af[1][1], vf1, o[1][sub]);
    }
    __builtin_amdgcn_s_setprio(0);
  }
#undef STAGEA

  float inv[2][4];
#pragma unroll
  for (int f = 0; f < 2; ++f) {
    float t = lsum[f];
    t += __shfl_xor(t, 16);
    t += __shfl_xor(t, 32);
#pragma unroll
    for (int r = 0; r < 4; ++r) inv[f][r] = 1.0f / __shfl(t, l4 * 4 + r);
  }

#pragma unroll
  for (int f = 0; f < 2; ++f) {
#pragma unroll
    for (int sub = 0; sub < 4; ++sub) {
#pragma unroll
      for (int r = 0; r < 4; ++r) {
        const int n = nrow0 + f * 16 + l4 * 4 + r;
        const size_t idx =
            ((size_t)(b * 1024 + n)) * 1024 + h * 64 + sub * 16 + l15;
        ao[idx] = (bf16)(o[f][sub][r] * inv[f][r]);
      }
    }
  }
}

// ---------------------------------------------------------------------------
// Cooperative mega-kernel: all 4 stages in ONE dispatch. 768 blocks = 3/CU
// co-resident (LDS 48 KB, launch_bounds caps VGPR ~168). grid.sync()
// (+ device fence) replaces the 3 inter-kernel launch/drain boundaries
// (~80 us of fixed overhead per the round-accounting across R0-R6).
// ---------------------------------------------------------------------------
__global__ __launch_bounds__(256, 3)
void mega(const float* __restrict__ x, const float* __restrict__ context,
          const int* __restrict__ mask, const float* __restrict__ Wq,
          const float* __restrict__ bq, const float* __restrict__ Wkv,
          const float* __restrict__ bkv, const float* __restrict__ Wp,
          const float* __restrict__ bp, float* __restrict__ out,
          char* __restrict__ ws) {
  __shared__ __align__(16) char smraw[49152];
  bf16* cb = (bf16*)(ws);
  bf16* aow = (bf16*)(ws);
  bf16* xb = (bf16*)(ws + (8ull << 20));
  bf16* BqkvT = (bf16*)(ws + (16ull << 20));
  bf16* qw = (bf16*)(ws + (22ull << 20));
  bf16* kw = (bf16*)(ws + (30ull << 20));
  bf16* vtw = (bf16*)(ws + (38ull << 20));
  u64* maskbits = (u64*)(ws + (46ull << 20));
  bf16* WpT = (bf16*)(ws + (46ull << 20) + (512ull << 10));

  cg::grid_group gg = cg::this_grid();
  const int bid = blockIdx.x;
  const int tid = threadIdx.x;

  // Phase 0: prep (5376 units over 768 blocks, 7 each).
#pragma unroll
  for (int i = 0; i < 7; ++i)
    prep_unit(smraw, bid + 768 * i, tid, Wq, Wkv, Wp, mask, context, x, BqkvT,
              WpT, maskbits, cb, xb);
  __threadfence();
  gg.sync();

  // Phase 1: QKV projection. bid -> (m = bid%32, nb = bid/32); XCD = bid%8
  // = m%8 (same map as the standalone launch).
  gemm_body<1, 128>(smraw, (bid & 31) * 128, (bid >> 5) * 128, xb, cb, BqkvT,
                    bq, bkv, qw, kw, vtw, nullptr);
  __threadfence();
  gg.sync();

  // Phase 2: attention (512 active; residency fixed -> exactly 2 active/CU).
  if (bid < 512) attn_body(smraw, bid & 63, bid >> 6, qw, kw, vtw, maskbits, aow);
  __threadfence();
  gg.sync();

  // Phase 3: output projection (512 active).
  if (bid < 512)
    gemm_body<0, 64>(smraw, (bid & 31) * 128, (bid >> 5) * 64, aow, nullptr,
                     WpT, bp, nullptr, nullptr, nullptr, nullptr, out);
}

// ---------------------------------------------------------------------------
// Fallback 4-kernel path (exact round-6 structure), used only if the
// cooperative launch is rejected (e.g. graph-capture incompatibility).
// ---------------------------------------------------------------------------
__global__ __launch_bounds__(256)
void prep_k(const float* __restrict__ Wq, const float* __restrict__ Wkv,
            const float* __restrict__ Wp, const int* __restrict__ mask,
            const float* __restrict__ context, const float* __restrict__ x,
            bf16* __restrict__ BqkvT, bf16* __restrict__ WpT,
            u64* __restrict__ maskbits, bf16* __restrict__ cb,
            bf16* __restrict__ xb) {
  __shared__ __align__(16) char smraw[9216];
  prep_unit(smraw, blockIdx.x, threadIdx.x, Wq, Wkv, Wp, mask, context, x,
            BqkvT, WpT, maskbits, cb, xb);
}

template <int EPI, int BN>
__global__ __launch_bounds__(256, 3)
void gemm_k(const bf16* __restrict__ A0, const bf16* __restrict__ A1,
            const bf16* __restrict__ Bt, const float* __restrict__ bias0,
            const float* __restrict__ bias1, bf16* __restrict__ oq,
            bf16* __restrict__ ok, bf16* __restrict__ ovt,
            float* __restrict__ outf) {
  __shared__ __align__(16) char smraw[16384 + 2 * BN * 32 * 2];
  gemm_body<EPI, BN>(smraw, blockIdx.x * 128, blockIdx.y * BN, A0, A1, Bt,
                     bias0, bias1, oq, ok, ovt, outf);
}

__global__ __launch_bounds__(256, 2)
void attn_k(const bf16* __restrict__ q, const bf16* __restrict__ k,
            const bf16* __restrict__ vT, const u64* __restrict__ maskbits,
            bf16* __restrict__ ao) {
  __shared__ __align__(16) char smraw[49152];
  attn_body(smraw, blockIdx.x, blockIdx.y, q, k, vT, maskbits, ao);
}

// ---------------------------------------------------------------------------
extern "C" void kernel_launch(void* const* d_in, const int* in_sizes, int n_in,
                              void* d_out, int out_size, void* d_ws,
                              size_t ws_size, hipStream_t stream) {
  const float* x = (const float*)d_in[0];        // [4,1024,1024]
  const float* context = (const float*)d_in[1];  // [4,1024,1024]
  const int* mask = (const int*)d_in[2];         // [4,1024,32,32]
  const float* Wq = (const float*)d_in[3];
  const float* bq = (const float*)d_in[4];
  const float* Wkv = (const float*)d_in[5];
  const float* bkv = (const float*)d_in[6];
  const float* Wp = (const float*)d_in[7];
  const float* bp = (const float*)d_in[8];
  float* out = (float*)d_out;                    // [4,1024,1024] f32

  // Workspace (48.5 MB): cb@0 (aow reuses), xb@8, BqkvT@16, qw@22, kw@30,
  // vtw@38, maskbits@46, WpT@46.5.
  char* ws = (char*)d_ws;

  void* margs[] = {(void*)&x,  (void*)&context, (void*)&mask, (void*)&Wq,
                   (void*)&bq, (void*)&Wkv,     (void*)&bkv,  (void*)&Wp,
                   (void*)&bp, (void*)&out,     (void*)&ws};
  hipError_t err = hipLaunchCooperativeKernel((const void*)mega, dim3(768),
                                              dim3(256), margs, 0, stream);
  if (err != hipSuccess) {
    (void)hipGetLastError();  // clear; fall back to 4-kernel path
    bf16* cb = (bf16*)(ws);
    bf16* aow = (bf16*)(ws);
    bf16* xb = (bf16*)(ws + (8ull << 20));
    bf16* BqkvT = (bf16*)(ws + (16ull << 20));
    bf16* qw = (bf16*)(ws + (22ull << 20));
    bf16* kw = (bf16*)(ws + (30ull << 20));
    bf16* vtw = (bf16*)(ws + (38ull << 20));
    u64* maskbits = (u64*)(ws + (46ull << 20));
    bf16* WpT = (bf16*)(ws + (46ull << 20) + (512ull << 10));
    const dim3 blk(256);
    prep_k<<<dim3(5376), blk, 0, stream>>>(Wq, Wkv, Wp, mask, context, x,
                                           BqkvT, WpT, maskbits, cb, xb);
    gemm_k<1, 128><<<dim3(32, 24), blk, 0, stream>>>(xb, cb, BqkvT, bq, bkv,
                                                     qw, kw, vtw, nullptr);
    attn_k<<<dim3(64, 8), blk, 0, stream>>>(qw, kw, vtw, maskbits, aow);
    gemm_k<0, 64><<<dim3(32, 16), blk, 0, stream>>>(aow, nullptr, WpT, bp,
                                                    nullptr, nullptr, nullptr,
                                                    nullptr, out);
  }
}

// Round 9
// 214.074 us; speedup vs baseline: 3.8803x; 3.8803x over previous
//
#include <hip/hip_runtime.h>

typedef __bf16 bf16;
typedef __bf16 bf16x8 __attribute__((ext_vector_type(8)));
typedef __bf16 bf16x4 __attribute__((ext_vector_type(4)));
typedef float f32x4 __attribute__((ext_vector_type(4)));
typedef unsigned long long u64;

#define MFMA16(a, b, c) __builtin_amdgcn_mfma_f32_16x16x32_bf16(a, b, c, 0, 0, 0)

// Async global->LDS, 16 B/lane; LDS dest = wave-uniform base + lane*16.
__device__ __forceinline__ void gl_lds16(const void* g, void* l) {
  __builtin_amdgcn_global_load_lds(
      (const __attribute__((address_space(1))) unsigned int*)g,
      (__attribute__((address_space(3))) unsigned int*)l, 16, 0, 0);
}

template <int N>
__device__ __forceinline__ void wait_vmcnt() {
  asm volatile("s_waitcnt vmcnt(%0)" ::"n"(N) : "memory");
}

// Compiler-fenced raw barrier (no vmcnt drain, unlike __syncthreads).
__device__ __forceinline__ void bar() {
  asm volatile("" ::: "memory");
  __builtin_amdgcn_s_barrier();
  asm volatile("" ::: "memory");
}

// ---------------------------------------------------------------------------
// Fused prep (round-3 proven):
//   blocks    0..1023: weight transpose+downcast (Wq,Wkv -> BqkvT; Wp -> WpT)
//   blocks 1024..1279: mask pack -> u64 bit-words
//   blocks 1280..3327: context f32 -> bf16 (cb)
//   blocks 3328..5375: x f32 -> bf16 (xb)
// ---------------------------------------------------------------------------
__global__ __launch_bounds__(256)
void prep_k(const float* __restrict__ Wq, const float* __restrict__ Wkv,
            const float* __restrict__ Wp, const int* __restrict__ mask,
            const float* __restrict__ context, const float* __restrict__ x,
            bf16* __restrict__ BqkvT, bf16* __restrict__ WpT,
            u64* __restrict__ maskbits, bf16* __restrict__ cb,
            bf16* __restrict__ xb) {
  const int bx = blockIdx.x;
  const int tid = threadIdx.x;
  if (bx >= 3328) {  // ---- x downcast
    const size_t i = ((size_t)(bx - 3328) * 256 + tid) * 8;
    f32x4 a0 = *(const f32x4*)(x + i);
    f32x4 a1 = *(const f32x4*)(x + i + 4);
    bf16x8 t;
#pragma unroll
    for (int j = 0; j < 4; ++j) { t[j] = (bf16)a0[j]; t[4 + j] = (bf16)a1[j]; }
    *(bf16x8*)(xb + i) = t;
    return;
  }
  if (bx >= 1280) {  // ---- context downcast
    const size_t i = ((size_t)(bx - 1280) * 256 + tid) * 8;
    f32x4 a0 = *(const f32x4*)(context + i);
    f32x4 a1 = *(const f32x4*)(context + i + 4);
    bf16x8 t;
#pragma unroll
    for (int j = 0; j < 4; ++j) { t[j] = (bf16)a0[j]; t[4 + j] = (bf16)a1[j]; }
    *(bf16x8*)(cb + i) = t;
    return;
  }
  if (bx >= 1024) {  // ---- mask pack
    const int idx = (bx - 1024) * 256 + tid;
    const int4* p = (const int4*)(mask + (size_t)idx * 64);
    u64 v = 0;
#pragma unroll
    for (int i = 0; i < 16; ++i) {
      int4 m = p[i];
      v |= (u64)(m.x != 0) << (4 * i);
      v |= (u64)(m.y != 0) << (4 * i + 1);
      v |= (u64)(m.z != 0) << (4 * i + 2);
      v |= (u64)(m.w != 0) << (4 * i + 3);
    }
    maskbits[idx] = v;
    return;
  }
  // ---- weight transpose tile
  const int ct = bx >> 4, rt = bx & 15;
  const float* src;
  bf16* dst;
  int C, c0, drow0;
  if (ct < 16) {
    src = Wq; C = 1024; c0 = ct * 64; dst = BqkvT; drow0 = c0;
  } else if (ct < 48) {
    src = Wkv; C = 2048; c0 = (ct - 16) * 64; dst = BqkvT; drow0 = 1024 + c0;
  } else {
    src = Wp; C = 1024; c0 = (ct - 48) * 64; dst = WpT; drow0 = c0;
  }
  __shared__ bf16 T[64][72];
  const int r0 = rt * 64;
#pragma unroll
  for (int i = 0; i < 2; ++i) {
    int c = i * 256 + tid;
    int row = c >> 3, col = (c & 7) * 8;
    const float* sp = &src[(size_t)(r0 + row) * C + c0 + col];
    f32x4 a0 = *(const f32x4*)sp;
    f32x4 a1 = *(const f32x4*)(sp + 4);
    bf16x8 t;
#pragma unroll
    for (int j = 0; j < 4; ++j) { t[j] = (bf16)a0[j]; t[4 + j] = (bf16)a1[j]; }
    *(bf16x8*)&T[row][col] = t;
  }
  __syncthreads();
#pragma unroll
  for (int i = 0; i < 2; ++i) {
    int c = i * 256 + tid;
    int orow = c >> 3, ocol = (c & 7) * 8;
    bf16x8 v;
#pragma unroll
    for (int j = 0; j < 8; ++j) v[j] = T[ocol + j][orow];
    *(bf16x8*)&dst[(size_t)(drow0 + orow) * 1024 + r0 + ocol] = v;
  }
}

// ---------------------------------------------------------------------------
// Pipelined GEMM v3 (round-4 proven for both QKV and OP): 128xBN, BK=32,
// 3 LDS buffers (tile t -> buf t%3), stages issued 2 tiles ahead, one raw
// barrier per K-step with counted s_waitcnt vmcnt(S) (never 0 in the loop).
// 16B-granule XOR swizzle on global source + ds_read column (0 conflicts).
// LDS: BN=128 -> 48 KB (3 blk/CU); BN=64 -> 36 KB (4 blk/CU).
// ---------------------------------------------------------------------------
template <int EPI, int BN>
__global__ __launch_bounds__(256, BN == 128 ? 3 : 4)
void gemm_p3(const bf16* __restrict__ A0, const bf16* __restrict__ A1,
             const bf16* __restrict__ Bt, const float* __restrict__ bias0,
             const float* __restrict__ bias1, bf16* __restrict__ oq,
             bf16* __restrict__ ok, bf16* __restrict__ ovt,
             float* __restrict__ outf) {
  constexpr int NJ = BN / 32;      // 16-wide n-frags per wave
  constexpr int S = 2 + BN / 64;   // global_load_lds per thread per stage
  __shared__ bf16 As[3][128][32];
  __shared__ bf16 Bs[3][BN][32];
  const int tid = threadIdx.x;
  const int lane = tid & 63;
  const int w = tid >> 6;
  const int wm = (w >> 1) * 64;
  const int wn = (w & 1) * (BN / 2);
  const int l15 = lane & 15, l4 = lane >> 4;
  const int lrow = lane >> 2;
  const int lcg = (lane & 3) ^ ((lrow >> 1) & 3);
  const int rdc = (l4 ^ ((l15 >> 1) & 3)) * 8;
  const int m0 = blockIdx.x * 128;  // m fastest -> XCD = m%8
  const int n0 = blockIdx.y * BN;

  const bf16* Asrc = (EPI == 1) ? ((n0 < 1024) ? A0 : A1) : A0;

  // Preload bias (issued before any staging -> retires before first wait).
  float bc[NJ];
#pragma unroll
  for (int j = 0; j < NJ; ++j) {
    const int col = n0 + wn + j * 16 + l15;
    if (EPI == 1) bc[j] = (col < 1024) ? bias0[col] : bias1[col - 1024];
    else bc[j] = bias0[col];
  }

  f32x4 acc[4][NJ] = {};

#define STAGE(kk, buf)                                                        \
  {                                                                           \
    _Pragma("unroll") for (int it = 0; it < 2; ++it) {                        \
      const int r = w * 32 + it * 16;                                         \
      gl_lds16(&Asrc[(size_t)(m0 + r + lrow) * 1024 + (kk) + lcg * 8],        \
               &As[buf][r][0]);                                               \
    }                                                                         \
    _Pragma("unroll") for (int it = 0; it < BN / 64; ++it) {                  \
      const int r = w * (BN / 4) + it * 16;                                   \
      gl_lds16(&Bt[(size_t)(n0 + r + lrow) * 1024 + (kk) + lcg * 8],          \
               &Bs[buf][r][0]);                                               \
    }                                                                         \
  }

#define COMPUTE(buf)                                                          \
  {                                                                           \
    bf16x8 af[4], bfr[NJ];                                                    \
    _Pragma("unroll") for (int i = 0; i < 4; ++i) af[i] =                     \
        *(const bf16x8*)&As[buf][wm + i * 16 + l15][rdc];                     \
    _Pragma("unroll") for (int j = 0; j < NJ; ++j) bfr[j] =                   \
        *(const bf16x8*)&Bs[buf][wn + j * 16 + l15][rdc];                     \
    _Pragma("unroll") for (int i = 0; i < 4; ++i)                             \
        _Pragma("unroll") for (int j = 0; j < NJ; ++j) acc[i][j] =            \
            MFMA16(af[i], bfr[j], acc[i][j]);                                 \
  }

  // Prologue: tiles 0 and 1 in flight (2S outstanding).
  STAGE(0, 0);
  STAGE(32, 1);
#pragma unroll 3
  for (int k = 0; k < 30; ++k) {
    wait_vmcnt<S>();  // tile k landed; tile k+1 stays in flight
    bar();
    STAGE((k + 2) * 32, (k + 2) % 3);  // buf free: tile k-1 fully read
    COMPUTE(k % 3);
  }
  wait_vmcnt<S>();
  bar();
  COMPUTE(0);
  wait_vmcnt<0>();
  bar();
  COMPUTE(1);
#undef STAGE
#undef COMPUTE

  const float SCALE2 = 0.18033688011112042f;  // 1/sqrt(64) * log2(e)
#pragma unroll
  for (int j = 0; j < NJ; ++j) {
    const int col = n0 + wn + j * 16 + l15;
#pragma unroll
    for (int i = 0; i < 4; ++i) {
#pragma unroll
      for (int r = 0; r < 4; ++r) {
        const int row = m0 + wm + i * 16 + l4 * 4 + r;
        const float v = acc[i][j][r] + bc[j];
        if (EPI == 0) {
          outf[(size_t)row * 1024 + col] = v;
        } else {
          const int b = row >> 10, n = row & 1023;
          if (col < 1024) {
            const int h = col >> 6, d = col & 63;
            oq[(((size_t)(b * 16 + h)) * 1024 + n) * 64 + d] =
                (bf16)(v * SCALE2);
          } else {
            const int ckv = col - 1024;
            const int s = ckv >> 10, c2 = ckv & 1023;
            const int h = c2 >> 6, d = c2 & 63;
            if (s == 0)
              ok[(((size_t)(b * 16 + h)) * 1024 + n) * 64 + d] = (bf16)v;
            else
              ovt[(((size_t)(b * 16 + h)) * 64 + d) * 1024 + n] = (bf16)v;
          }
        }
      }
    }
  }
}

// ---------------------------------------------------------------------------
// Attention v3.1 (round-6 v3 + mask prefetch): 32 q-rows/wave (QBLK=128,
// grid (64,8), 2 blk/CU), swapped QK^T, K/V frags shared across 2 q-frags,
// XOR-swizzled gl_lds staging, dbuf, one __syncthreads per mt.
// Mask words for mt are loaded one iteration AHEAD into registers: vmcnt is
// an in-order FIFO, so the old mid-iteration mask wait also drained the just
// -issued K/V staging loads, shrinking their in-flight window to the QK
// phase. Prefetch removes every mid-iteration vmem wait. LDS 48 KB.
// ---------------------------------------------------------------------------
__global__ __launch_bounds__(256, 2)
void attn_kernel(const bf16* __restrict__ q, const bf16* __restrict__ k,
                 const bf16* __restrict__ vT, const u64* __restrict__ maskbits,
                 bf16* __restrict__ ao) {
  const int bh = blockIdx.x;
  const int ntile = blockIdx.y;  // 0..7
  const int b = bh >> 4, h = bh & 15;
  const int tid = threadIdx.x;
  const int lane = tid & 63;
  const int w = tid >> 6;
  const int l15 = lane & 15, l4 = lane >> 4;

  __shared__ bf16 Ks[2][64][64];
  __shared__ bf16 Vts[2][64][64];
  __shared__ bf16 Pw[4][32][64];

  const size_t base = (size_t)bh * 65536;
  const int nrow0 = ntile * 128 + w * 32;

  // Q B-fragments for both q-frags (f in {0,1}; q-row = nrow0+f*16+l15).
  bf16x8 qf[2][2];
#pragma unroll
  for (int f = 0; f < 2; ++f)
#pragma unroll
    for (int ks = 0; ks < 2; ++ks)
      qf[f][ks] = *(const bf16x8*)&q[base +
                                     (size_t)(nrow0 + f * 16 + l15) * 64 +
                                     ks * 32 + l4 * 8];

  // Mask rows for both q-frags (row stride = 16 u64).
  const u64* mb = maskbits + (size_t)(b * 1024 + nrow0 + l15) * 16;

  // K/V staging: lane -> row (i>>3), phys granule i&7; source fetches
  // logical granule (i&7)^(row&7) so phys = logical ^ (row&7).
  const int srow = lane >> 3;
  const int sgl = (lane & 7) ^ srow;
  const bf16* kp = &k[base + (size_t)(w * 16 + srow) * 64 + sgl * 8];
  const bf16* vp = &vT[base + (size_t)(w * 16 + srow) * 1024 + sgl * 8];

  // Fragment read columns: logical granule ks*4+l4 -> phys ^= (l15&7).
  const int rc0 = ((0 + l4) ^ (l15 & 7)) * 8;
  const int rc1 = ((4 + l4) ^ (l15 & 7)) * 8;

  f32x4 o[2][4] = {};
  float lsum[2] = {0.0f, 0.0f};

#define STAGEA(mt_, buf_)                                                     \
  {                                                                           \
    _Pragma("unroll") for (int it = 0; it < 2; ++it) {                        \
      gl_lds16(kp + (size_t)((mt_)*64 + it * 8) * 64,                         \
               &Ks[buf_][w * 16 + it * 8][0]);                                \
      gl_lds16(vp + (size_t)(it * 8) * 1024 + (mt_)*64,                       \
               &Vts[buf_][w * 16 + it * 8][0]);                               \
    }                                                                         \
  }

  STAGEA(0, 0);
  // Prologue mask prefetch for mt = 0.
  u64 wm0 = mb[0];
  u64 wm1 = mb[256];
  for (int mt = 0; mt < 16; ++mt) {
    const int cur = mt & 1;
    __syncthreads();  // drains staging for tile mt (and mask prefetch)
    if (mt < 15) STAGEA(mt + 1, cur ^ 1);  // in flight across compute
    // Prefetch next iteration's mask words (consumed NEXT mt; no vmem wait
    // inside this iteration's compute).
    u64 nm0 = 0, nm1 = 0;
    if (mt < 15) {
      nm0 = mb[mt + 1];
      nm1 = mb[256 + mt + 1];
    }

    // S^T: lane holds q = f*16+l15, k = sub*16 + l4*4 + r. K-frags shared
    // across both q-frags.
    f32x4 s[2][4];
#pragma unroll
    for (int f = 0; f < 2; ++f)
#pragma unroll
      for (int sub = 0; sub < 4; ++sub)
        s[f][sub] = f32x4{-12.f, -12.f, -12.f, -12.f};
    __builtin_amdgcn_s_setprio(1);
#pragma unroll
    for (int sub = 0; sub < 4; ++sub) {
      bf16x8 kf0 = *(const bf16x8*)&Ks[cur][sub * 16 + l15][rc0];
      bf16x8 kf1 = *(const bf16x8*)&Ks[cur][sub * 16 + l15][rc1];
      s[0][sub] = MFMA16(kf0, qf[0][0], s[0][sub]);
      s[0][sub] = MFMA16(kf1, qf[0][1], s[0][sub]);
      s[1][sub] = MFMA16(kf0, qf[1][0], s[1][sub]);
      s[1][sub] = MFMA16(kf1, qf[1][1], s[1][sub]);
    }
    __builtin_amdgcn_s_setprio(0);

    // Softmax + P pack: one ds_write_b64 per (f, sub). Masks from regs.
#pragma unroll
    for (int f = 0; f < 2; ++f) {
      const u64 wmt = f ? wm1 : wm0;
#pragma unroll
      for (int sub = 0; sub < 4; ++sub) {
        const int kbit = sub * 16 + l4 * 4;
        float p[4];
#pragma unroll
        for (int r = 0; r < 4; ++r) {
          float e = exp2f(s[f][sub][r]);
          p[r] = ((wmt >> (kbit + r)) & 1) ? e : 0.0f;
        }
        lsum[f] += (p[0] + p[1]) + (p[2] + p[3]);
        bf16x4 pv;
#pragma unroll
        for (int r = 0; r < 4; ++r) pv[r] = (bf16)p[r];
        const int gw = sub * 2 + (l4 >> 1);
        char* pd = (char*)&Pw[w][f * 16 + l15][0] +
                   ((gw ^ (l15 & 7)) * 16 + (l4 & 1) * 8);
        *(bf16x4*)pd = pv;
      }
    }

    // PV: V-frags shared across both q-frags.
    bf16x8 af[2][2];
#pragma unroll
    for (int f = 0; f < 2; ++f) {
      af[f][0] = *(const bf16x8*)&Pw[w][f * 16 + l15][rc0];
      af[f][1] = *(const bf16x8*)&Pw[w][f * 16 + l15][rc1];
    }
    __builtin_amdgcn_s_setprio(1);
#pragma unroll
    for (int sub = 0; sub < 4; ++sub) {
      bf16x8 vf0 = *(const bf16x8*)&Vts[cur][sub * 16 + l15][rc0];
      bf16x8 vf1 = *(const bf16x8*)&Vts[cur][sub * 16 + l15][rc1];
      o[0][sub] = MFMA16(af[0][0], vf0, o[0][sub]);
      o[0][sub] = MFMA16(af[0][1], vf1, o[0][sub]);
      o[1][sub] = MFMA16(af[1][0], vf0, o[1][sub]);
      o[1][sub] = MFMA16(af[1][1], vf1, o[1][sub]);
    }
    __builtin_amdgcn_s_setprio(0);

    wm0 = nm0;
    wm1 = nm1;
  }
#undef STAGEA

  // lsum at lane q=f*16+l15: reduce over l4 groups, redistribute to output
  // layout (q = f*16 + l4*4 + r).
  float inv[2][4];
#pragma unroll
  for (int f = 0; f < 2; ++f) {
    float t = lsum[f];
    t += __shfl_xor(t, 16);
    t += __shfl_xor(t, 32);
#pragma unroll
    for (int r = 0; r < 4; ++r) inv[f][r] = 1.0f / __shfl(t, l4 * 4 + r);
  }

#pragma unroll
  for (int f = 0; f < 2; ++f) {
#pragma unroll
    for (int sub = 0; sub < 4; ++sub) {
#pragma unroll
      for (int r = 0; r < 4; ++r) {
        const int n = nrow0 + f * 16 + l4 * 4 + r;
        const size_t idx =
            ((size_t)(b * 1024 + n)) * 1024 + h * 64 + sub * 16 + l15;
        ao[idx] = (bf16)(o[f][sub][r] * inv[f][r]);
      }
    }
  }
}

// ---------------------------------------------------------------------------
extern "C" void kernel_launch(void* const* d_in, const int* in_sizes, int n_in,
                              void* d_out, int out_size, void* d_ws,
                              size_t ws_size, hipStream_t stream) {
  const float* x = (const float*)d_in[0];        // [4,1024,1024]
  const float* context = (const float*)d_in[1];  // [4,1024,1024]
  const int* mask = (const int*)d_in[2];         // [4,1024,32,32]
  const float* Wq = (const float*)d_in[3];
  const float* bq = (const float*)d_in[4];
  const float* Wkv = (const float*)d_in[5];
  const float* bkv = (const float*)d_in[6];
  const float* Wp = (const float*)d_in[7];
  const float* bp = (const float*)d_in[8];
  float* out = (float*)d_out;                    // [4,1024,1024] f32

  // Workspace (48.5 MB):
  //  @0    (8 MB): cb (prep->QKV), dead after QKV -> aow reuses it
  //  @8    (8 MB): xb (prep->QKV), dead after QKV
  //  @16   (6 MB): BqkvT (prep->QKV)
  //  @22   (8 MB): qw   @30 (8 MB): kw   @38 (8 MB): vtw
  //  @46 (0.5 MB): maskbits   @46.5 (2 MB): WpT
  char* ws = (char*)d_ws;
  bf16* cb = (bf16*)(ws);
  bf16* aow = (bf16*)(ws);
  bf16* xb = (bf16*)(ws + (8ull << 20));
  bf16* BqkvT = (bf16*)(ws + (16ull << 20));
  bf16* qw = (bf16*)(ws + (22ull << 20));
  bf16* kw = (bf16*)(ws + (30ull << 20));
  bf16* vtw = (bf16*)(ws + (38ull << 20));
  u64* maskbits = (u64*)(ws + (46ull << 20));
  bf16* WpT = (bf16*)(ws + (46ull << 20) + (512ull << 10));

  const dim3 blk(256);

  // Prep: weight transposes + mask pack + context/x downcast, one launch.
  prep_k<<<dim3(5376), blk, 0, stream>>>(Wq, Wkv, Wp, mask, context, x, BqkvT,
                                         WpT, maskbits, cb, xb);

  // Fused QKV projection: pipelined v3, grid (m=32, n=24), 3 blk/CU.
  gemm_p3<1, 128><<<dim3(32, 24), blk, 0, stream>>>(xb, cb, BqkvT, bq, bkv,
                                                    qw, kw, vtw, nullptr);

  // Attention v3.1: QBLK=128, grid (bh=64, ntile=8) -> XCD = bh%8.
  attn_kernel<<<dim3(64, 8), blk, 0, stream>>>(qw, kw, vtw, maskbits, aow);

  // Output projection: pipelined v3, grid (m=32, n=16), 4 blk/CU.
  gemm_p3<0, 64><<<dim3(32, 16), blk, 0, stream>>>(aow, nullptr, WpT, bp,
                                                   nullptr, nullptr, nullptr,
                                                   nullptr, out);
}

// Round 10
// 205.024 us; speedup vs baseline: 4.0516x; 1.0441x over previous
//
#include <hip/hip_runtime.h>

typedef __bf16 bf16;
typedef __bf16 bf16x8 __attribute__((ext_vector_type(8)));
typedef __bf16 bf16x4 __attribute__((ext_vector_type(4)));
typedef float f32x4 __attribute__((ext_vector_type(4)));
typedef unsigned long long u64;

#define MFMA16(a, b, c) __builtin_amdgcn_mfma_f32_16x16x32_bf16(a, b, c, 0, 0, 0)

// Async global->LDS, 16 B/lane; LDS dest = wave-uniform base + lane*16.
__device__ __forceinline__ void gl_lds16(const void* g, void* l) {
  __builtin_amdgcn_global_load_lds(
      (const __attribute__((address_space(1))) unsigned int*)g,
      (__attribute__((address_space(3))) unsigned int*)l, 16, 0, 0);
}

template <int N>
__device__ __forceinline__ void wait_vmcnt() {
  asm volatile("s_waitcnt vmcnt(%0)" ::"n"(N) : "memory");
}

// Compiler-fenced raw barrier (no vmcnt drain, unlike __syncthreads).
__device__ __forceinline__ void bar() {
  asm volatile("" ::: "memory");
  __builtin_amdgcn_s_barrier();
  asm volatile("" ::: "memory");
}

// Hardware exp2: single v_exp_f32 (libm exp2f without -ffast-math lowers to
// a guarded OCML sequence -- the attn kernel is VALU-bound on exactly this).
__device__ __forceinline__ float hw_exp2(float x) {
#if __has_builtin(__builtin_amdgcn_exp2f)
  return __builtin_amdgcn_exp2f(x);
#else
  float r;
  asm("v_exp_f32 %0, %1" : "=v"(r) : "v"(x));
  return r;
#endif
}

// ---------------------------------------------------------------------------
// Fused prep (round-3 proven):
//   blocks    0..1023: weight transpose+downcast (Wq,Wkv -> BqkvT; Wp -> WpT)
//   blocks 1024..1279: mask pack -> u64 bit-words
//   blocks 1280..3327: context f32 -> bf16 (cb)
//   blocks 3328..5375: x f32 -> bf16 (xb)
// ---------------------------------------------------------------------------
__global__ __launch_bounds__(256)
void prep_k(const float* __restrict__ Wq, const float* __restrict__ Wkv,
            const float* __restrict__ Wp, const int* __restrict__ mask,
            const float* __restrict__ context, const float* __restrict__ x,
            bf16* __restrict__ BqkvT, bf16* __restrict__ WpT,
            u64* __restrict__ maskbits, bf16* __restrict__ cb,
            bf16* __restrict__ xb) {
  const int bx = blockIdx.x;
  const int tid = threadIdx.x;
  if (bx >= 3328) {  // ---- x downcast
    const size_t i = ((size_t)(bx - 3328) * 256 + tid) * 8;
    f32x4 a0 = *(const f32x4*)(x + i);
    f32x4 a1 = *(const f32x4*)(x + i + 4);
    bf16x8 t;
#pragma unroll
    for (int j = 0; j < 4; ++j) { t[j] = (bf16)a0[j]; t[4 + j] = (bf16)a1[j]; }
    *(bf16x8*)(xb + i) = t;
    return;
  }
  if (bx >= 1280) {  // ---- context downcast
    const size_t i = ((size_t)(bx - 1280) * 256 + tid) * 8;
    f32x4 a0 = *(const f32x4*)(context + i);
    f32x4 a1 = *(const f32x4*)(context + i + 4);
    bf16x8 t;
#pragma unroll
    for (int j = 0; j < 4; ++j) { t[j] = (bf16)a0[j]; t[4 + j] = (bf16)a1[j]; }
    *(bf16x8*)(cb + i) = t;
    return;
  }
  if (bx >= 1024) {  // ---- mask pack
    const int idx = (bx - 1024) * 256 + tid;
    const int4* p = (const int4*)(mask + (size_t)idx * 64);
    u64 v = 0;
#pragma unroll
    for (int i = 0; i < 16; ++i) {
      int4 m = p[i];
      v |= (u64)(m.x != 0) << (4 * i);
      v |= (u64)(m.y != 0) << (4 * i + 1);
      v |= (u64)(m.z != 0) << (4 * i + 2);
      v |= (u64)(m.w != 0) << (4 * i + 3);
    }
    maskbits[idx] = v;
    return;
  }
  // ---- weight transpose tile
  const int ct = bx >> 4, rt = bx & 15;
  const float* src;
  bf16* dst;
  int C, c0, drow0;
  if (ct < 16) {
    src = Wq; C = 1024; c0 = ct * 64; dst = BqkvT; drow0 = c0;
  } else if (ct < 48) {
    src = Wkv; C = 2048; c0 = (ct - 16) * 64; dst = BqkvT; drow0 = 1024 + c0;
  } else {
    src = Wp; C = 1024; c0 = (ct - 48) * 64; dst = WpT; drow0 = c0;
  }
  __shared__ bf16 T[64][72];
  const int r0 = rt * 64;
#pragma unroll
  for (int i = 0; i < 2; ++i) {
    int c = i * 256 + tid;
    int row = c >> 3, col = (c & 7) * 8;
    const float* sp = &src[(size_t)(r0 + row) * C + c0 + col];
    f32x4 a0 = *(const f32x4*)sp;
    f32x4 a1 = *(const f32x4*)(sp + 4);
    bf16x8 t;
#pragma unroll
    for (int j = 0; j < 4; ++j) { t[j] = (bf16)a0[j]; t[4 + j] = (bf16)a1[j]; }
    *(bf16x8*)&T[row][col] = t;
  }
  __syncthreads();
#pragma unroll
  for (int i = 0; i < 2; ++i) {
    int c = i * 256 + tid;
    int orow = c >> 3, ocol = (c & 7) * 8;
    bf16x8 v;
#pragma unroll
    for (int j = 0; j < 8; ++j) v[j] = T[ocol + j][orow];
    *(bf16x8*)&dst[(size_t)(drow0 + orow) * 1024 + r0 + ocol] = v;
  }
}

// ---------------------------------------------------------------------------
// Pipelined GEMM v3 (round-4 proven for both QKV and OP): 128xBN, BK=32,
// 3 LDS buffers (tile t -> buf t%3), stages issued 2 tiles ahead, one raw
// barrier per K-step with counted s_waitcnt vmcnt(S) (never 0 in the loop).
// 16B-granule XOR swizzle on global source + ds_read column (0 conflicts).
// LDS: BN=128 -> 48 KB (3 blk/CU); BN=64 -> 36 KB (4 blk/CU).
// ---------------------------------------------------------------------------
template <int EPI, int BN>
__global__ __launch_bounds__(256, BN == 128 ? 3 : 4)
void gemm_p3(const bf16* __restrict__ A0, const bf16* __restrict__ A1,
             const bf16* __restrict__ Bt, const float* __restrict__ bias0,
             const float* __restrict__ bias1, bf16* __restrict__ oq,
             bf16* __restrict__ ok, bf16* __restrict__ ovt,
             float* __restrict__ outf) {
  constexpr int NJ = BN / 32;      // 16-wide n-frags per wave
  constexpr int S = 2 + BN / 64;   // global_load_lds per thread per stage
  __shared__ bf16 As[3][128][32];
  __shared__ bf16 Bs[3][BN][32];
  const int tid = threadIdx.x;
  const int lane = tid & 63;
  const int w = tid >> 6;
  const int wm = (w >> 1) * 64;
  const int wn = (w & 1) * (BN / 2);
  const int l15 = lane & 15, l4 = lane >> 4;
  const int lrow = lane >> 2;
  const int lcg = (lane & 3) ^ ((lrow >> 1) & 3);
  const int rdc = (l4 ^ ((l15 >> 1) & 3)) * 8;
  const int m0 = blockIdx.x * 128;  // m fastest -> XCD = m%8
  const int n0 = blockIdx.y * BN;

  const bf16* Asrc = (EPI == 1) ? ((n0 < 1024) ? A0 : A1) : A0;

  // Preload bias (issued before any staging -> retires before first wait).
  float bc[NJ];
#pragma unroll
  for (int j = 0; j < NJ; ++j) {
    const int col = n0 + wn + j * 16 + l15;
    if (EPI == 1) bc[j] = (col < 1024) ? bias0[col] : bias1[col - 1024];
    else bc[j] = bias0[col];
  }

  f32x4 acc[4][NJ] = {};

#define STAGE(kk, buf)                                                        \
  {                                                                           \
    _Pragma("unroll") for (int it = 0; it < 2; ++it) {                        \
      const int r = w * 32 + it * 16;                                         \
      gl_lds16(&Asrc[(size_t)(m0 + r + lrow) * 1024 + (kk) + lcg * 8],        \
               &As[buf][r][0]);                                               \
    }                                                                         \
    _Pragma("unroll") for (int it = 0; it < BN / 64; ++it) {                  \
      const int r = w * (BN / 4) + it * 16;                                   \
      gl_lds16(&Bt[(size_t)(n0 + r + lrow) * 1024 + (kk) + lcg * 8],          \
               &Bs[buf][r][0]);                                               \
    }                                                                         \
  }

#define COMPUTE(buf)                                                          \
  {                                                                           \
    bf16x8 af[4], bfr[NJ];                                                    \
    _Pragma("unroll") for (int i = 0; i < 4; ++i) af[i] =                     \
        *(const bf16x8*)&As[buf][wm + i * 16 + l15][rdc];                     \
    _Pragma("unroll") for (int j = 0; j < NJ; ++j) bfr[j] =                   \
        *(const bf16x8*)&Bs[buf][wn + j * 16 + l15][rdc];                     \
    _Pragma("unroll") for (int i = 0; i < 4; ++i)                             \
        _Pragma("unroll") for (int j = 0; j < NJ; ++j) acc[i][j] =            \
            MFMA16(af[i], bfr[j], acc[i][j]);                                 \
  }

  // Prologue: tiles 0 and 1 in flight (2S outstanding).
  STAGE(0, 0);
  STAGE(32, 1);
#pragma unroll 3
  for (int k = 0; k < 30; ++k) {
    wait_vmcnt<S>();  // tile k landed; tile k+1 stays in flight
    bar();
    STAGE((k + 2) * 32, (k + 2) % 3);  // buf free: tile k-1 fully read
    COMPUTE(k % 3);
  }
  wait_vmcnt<S>();
  bar();
  COMPUTE(0);
  wait_vmcnt<0>();
  bar();
  COMPUTE(1);
#undef STAGE
#undef COMPUTE

  const float SCALE2 = 0.18033688011112042f;  // 1/sqrt(64) * log2(e)
#pragma unroll
  for (int j = 0; j < NJ; ++j) {
    const int col = n0 + wn + j * 16 + l15;
#pragma unroll
    for (int i = 0; i < 4; ++i) {
#pragma unroll
      for (int r = 0; r < 4; ++r) {
        const int row = m0 + wm + i * 16 + l4 * 4 + r;
        const float v = acc[i][j][r] + bc[j];
        if (EPI == 0) {
          outf[(size_t)row * 1024 + col] = v;
        } else {
          const int b = row >> 10, n = row & 1023;
          if (col < 1024) {
            const int h = col >> 6, d = col & 63;
            oq[(((size_t)(b * 16 + h)) * 1024 + n) * 64 + d] =
                (bf16)(v * SCALE2);
          } else {
            const int ckv = col - 1024;
            const int s = ckv >> 10, c2 = ckv & 1023;
            const int h = c2 >> 6, d = c2 & 63;
            if (s == 0)
              ok[(((size_t)(b * 16 + h)) * 1024 + n) * 64 + d] = (bf16)v;
            else
              ovt[(((size_t)(b * 16 + h)) * 64 + d) * 1024 + n] = (bf16)v;
          }
        }
      }
    }
  }
}

// ---------------------------------------------------------------------------
// Attention v3.2 (v3.1 + VALU diet): the kernel is VALU-bound (R9 counters:
// VALUBusy 50%, MfmaUtil 14%, HBM 6%). Three cuts, numerically bit-neutral:
//  1. hw_exp2 (single v_exp_f32) instead of libm exp2f (OCML guarded seq).
//  2. Mask test on 32-bit words: one nibble extract per (f,sub) instead of a
//     64-bit shift per P-value.
//  3. Dropped the -12 fixed-max bias (cancels exactly in p/sum) and pass an
//     inline-zero C to the first MFMA -> kills 32 v_mov of s-init per mt.
// Structure unchanged: QBLK=128, grid (64,8), swapped QK^T, shared K/V frags,
// XOR-swizzled gl_lds staging, dbuf, mask prefetch, 1 syncthreads/mt.
// ---------------------------------------------------------------------------
__global__ __launch_bounds__(256, 2)
void attn_kernel(const bf16* __restrict__ q, const bf16* __restrict__ k,
                 const bf16* __restrict__ vT, const u64* __restrict__ maskbits,
                 bf16* __restrict__ ao) {
  const int bh = blockIdx.x;
  const int ntile = blockIdx.y;  // 0..7
  const int b = bh >> 4, h = bh & 15;
  const int tid = threadIdx.x;
  const int lane = tid & 63;
  const int w = tid >> 6;
  const int l15 = lane & 15, l4 = lane >> 4;

  __shared__ bf16 Ks[2][64][64];
  __shared__ bf16 Vts[2][64][64];
  __shared__ bf16 Pw[4][32][64];

  const size_t base = (size_t)bh * 65536;
  const int nrow0 = ntile * 128 + w * 32;

  // Q B-fragments for both q-frags (f in {0,1}; q-row = nrow0+f*16+l15).
  bf16x8 qf[2][2];
#pragma unroll
  for (int f = 0; f < 2; ++f)
#pragma unroll
    for (int ks = 0; ks < 2; ++ks)
      qf[f][ks] = *(const bf16x8*)&q[base +
                                     (size_t)(nrow0 + f * 16 + l15) * 64 +
                                     ks * 32 + l4 * 8];

  // Mask rows for both q-frags (row stride = 16 u64).
  const u64* mb = maskbits + (size_t)(b * 1024 + nrow0 + l15) * 16;

  // K/V staging: lane -> row (i>>3), phys granule i&7; source fetches
  // logical granule (i&7)^(row&7) so phys = logical ^ (row&7).
  const int srow = lane >> 3;
  const int sgl = (lane & 7) ^ srow;
  const bf16* kp = &k[base + (size_t)(w * 16 + srow) * 64 + sgl * 8];
  const bf16* vp = &vT[base + (size_t)(w * 16 + srow) * 1024 + sgl * 8];

  // Fragment read columns: logical granule ks*4+l4 -> phys ^= (l15&7).
  const int rc0 = ((0 + l4) ^ (l15 & 7)) * 8;
  const int rc1 = ((4 + l4) ^ (l15 & 7)) * 8;

  // Nibble shift amounts for the 32-bit mask words (per-lane, loop-invariant).
  const int sh0 = l4 * 4;        // sub even: bits (sub&1)==0
  const int sh1 = 16 + l4 * 4;   // sub odd

  f32x4 o[2][4] = {};
  float lsum[2] = {0.0f, 0.0f};

#define STAGEA(mt_, buf_)                                                     \
  {                                                                           \
    _Pragma("unroll") for (int it = 0; it < 2; ++it) {                        \
      gl_lds16(kp + (size_t)((mt_)*64 + it * 8) * 64,                         \
               &Ks[buf_][w * 16 + it * 8][0]);                                \
      gl_lds16(vp + (size_t)(it * 8) * 1024 + (mt_)*64,                       \
               &Vts[buf_][w * 16 + it * 8][0]);                               \
    }                                                                         \
  }

  STAGEA(0, 0);
  // Prologue mask prefetch for mt = 0.
  u64 wm0 = mb[0];
  u64 wm1 = mb[256];
  for (int mt = 0; mt < 16; ++mt) {
    const int cur = mt & 1;
    __syncthreads();  // drains staging for tile mt (and mask prefetch)
    if (mt < 15) STAGEA(mt + 1, cur ^ 1);  // in flight across compute
    // Prefetch next iteration's mask words (consumed NEXT mt).
    u64 nm0 = 0, nm1 = 0;
    if (mt < 15) {
      nm0 = mb[mt + 1];
      nm1 = mb[256 + mt + 1];
    }

    // S^T: lane holds q = f*16+l15, k = sub*16 + l4*4 + r. K-frags shared
    // across both q-frags. First MFMA of each chain takes inline-zero C.
    f32x4 s[2][4];
    __builtin_amdgcn_s_setprio(1);
#pragma unroll
    for (int sub = 0; sub < 4; ++sub) {
      bf16x8 kf0 = *(const bf16x8*)&Ks[cur][sub * 16 + l15][rc0];
      bf16x8 kf1 = *(const bf16x8*)&Ks[cur][sub * 16 + l15][rc1];
      s[0][sub] = MFMA16(kf0, qf[0][0], (f32x4)0.0f);
      s[0][sub] = MFMA16(kf1, qf[0][1], s[0][sub]);
      s[1][sub] = MFMA16(kf0, qf[1][0], (f32x4)0.0f);
      s[1][sub] = MFMA16(kf1, qf[1][1], s[1][sub]);
    }
    __builtin_amdgcn_s_setprio(0);

    // Softmax + P pack: one ds_write_b64 per (f, sub). 32-bit nibble mask.
#pragma unroll
    for (int f = 0; f < 2; ++f) {
      const u64 wmt = f ? wm1 : wm0;
      const unsigned mlo = (unsigned)wmt;
      const unsigned mhi = (unsigned)(wmt >> 32);
#pragma unroll
      for (int sub = 0; sub < 4; ++sub) {
        const unsigned word = (sub < 2) ? mlo : mhi;
        const unsigned nib = (word >> ((sub & 1) ? sh1 : sh0)) & 15u;
        float p[4];
#pragma unroll
        for (int r = 0; r < 4; ++r) {
          float e = hw_exp2(s[f][sub][r]);
          p[r] = ((nib >> r) & 1u) ? e : 0.0f;
        }
        lsum[f] += (p[0] + p[1]) + (p[2] + p[3]);
        bf16x4 pv;
#pragma unroll
        for (int r = 0; r < 4; ++r) pv[r] = (bf16)p[r];
        const int gw = sub * 2 + (l4 >> 1);
        char* pd = (char*)&Pw[w][f * 16 + l15][0] +
                   ((gw ^ (l15 & 7)) * 16 + (l4 & 1) * 8);
        *(bf16x4*)pd = pv;
      }
    }

    // PV: V-frags shared across both q-frags.
    bf16x8 af[2][2];
#pragma unroll
    for (int f = 0; f < 2; ++f) {
      af[f][0] = *(const bf16x8*)&Pw[w][f * 16 + l15][rc0];
      af[f][1] = *(const bf16x8*)&Pw[w][f * 16 + l15][rc1];
    }
    __builtin_amdgcn_s_setprio(1);
#pragma unroll
    for (int sub = 0; sub < 4; ++sub) {
      bf16x8 vf0 = *(const bf16x8*)&Vts[cur][sub * 16 + l15][rc0];
      bf16x8 vf1 = *(const bf16x8*)&Vts[cur][sub * 16 + l15][rc1];
      o[0][sub] = MFMA16(af[0][0], vf0, o[0][sub]);
      o[0][sub] = MFMA16(af[0][1], vf1, o[0][sub]);
      o[1][sub] = MFMA16(af[1][0], vf0, o[1][sub]);
      o[1][sub] = MFMA16(af[1][1], vf1, o[1][sub]);
    }
    __builtin_amdgcn_s_setprio(0);

    wm0 = nm0;
    wm1 = nm1;
  }
#undef STAGEA

  // lsum at lane q=f*16+l15: reduce over l4 groups, redistribute to output
  // layout (q = f*16 + l4*4 + r).
  float inv[2][4];
#pragma unroll
  for (int f = 0; f < 2; ++f) {
    float t = lsum[f];
    t += __shfl_xor(t, 16);
    t += __shfl_xor(t, 32);
#pragma unroll
    for (int r = 0; r < 4; ++r) inv[f][r] = 1.0f / __shfl(t, l4 * 4 + r);
  }

#pragma unroll
  for (int f = 0; f < 2; ++f) {
#pragma unroll
    for (int sub = 0; sub < 4; ++sub) {
#pragma unroll
      for (int r = 0; r < 4; ++r) {
        const int n = nrow0 + f * 16 + l4 * 4 + r;
        const size_t idx =
            ((size_t)(b * 1024 + n)) * 1024 + h * 64 + sub * 16 + l15;
        ao[idx] = (bf16)(o[f][sub][r] * inv[f][r]);
      }
    }
  }
}

// ---------------------------------------------------------------------------
extern "C" void kernel_launch(void* const* d_in, const int* in_sizes, int n_in,
                              void* d_out, int out_size, void* d_ws,
                              size_t ws_size, hipStream_t stream) {
  const float* x = (const float*)d_in[0];        // [4,1024,1024]
  const float* context = (const float*)d_in[1];  // [4,1024,1024]
  const int* mask = (const int*)d_in[2];         // [4,1024,32,32]
  const float* Wq = (const float*)d_in[3];
  const float* bq = (const float*)d_in[4];
  const float* Wkv = (const float*)d_in[5];
  const float* bkv = (const float*)d_in[6];
  const float* Wp = (const float*)d_in[7];
  const float* bp = (const float*)d_in[8];
  float* out = (float*)d_out;                    // [4,1024,1024] f32

  // Workspace (48.5 MB):
  //  @0    (8 MB): cb (prep->QKV), dead after QKV -> aow reuses it
  //  @8    (8 MB): xb (prep->QKV), dead after QKV
  //  @16   (6 MB): BqkvT (prep->QKV)
  //  @22   (8 MB): qw   @30 (8 MB): kw   @38 (8 MB): vtw
  //  @46 (0.5 MB): maskbits   @46.5 (2 MB): WpT
  char* ws = (char*)d_ws;
  bf16* cb = (bf16*)(ws);
  bf16* aow = (bf16*)(ws);
  bf16* xb = (bf16*)(ws + (8ull << 20));
  bf16* BqkvT = (bf16*)(ws + (16ull << 20));
  bf16* qw = (bf16*)(ws + (22ull << 20));
  bf16* kw = (bf16*)(ws + (30ull << 20));
  bf16* vtw = (bf16*)(ws + (38ull << 20));
  u64* maskbits = (u64*)(ws + (46ull << 20));
  bf16* WpT = (bf16*)(ws + (46ull << 20) + (512ull << 10));

  const dim3 blk(256);

  // Prep: weight transposes + mask pack + context/x downcast, one launch.
  prep_k<<<dim3(5376), blk, 0, stream>>>(Wq, Wkv, Wp, mask, context, x, BqkvT,
                                         WpT, maskbits, cb, xb);

  // Fused QKV projection: pipelined v3, grid (m=32, n=24), 3 blk/CU.
  gemm_p3<1, 128><<<dim3(32, 24), blk, 0, stream>>>(xb, cb, BqkvT, bq, bkv,
                                                    qw, kw, vtw, nullptr);

  // Attention v3.2: QBLK=128, grid (bh=64, ntile=8) -> XCD = bh%8.
  attn_kernel<<<dim3(64, 8), blk, 0, stream>>>(qw, kw, vtw, maskbits, aow);

  // Output projection: pipelined v3, grid (m=32, n=16), 4 blk/CU.
  gemm_p3<0, 64><<<dim3(32, 16), blk, 0, stream>>>(aow, nullptr, WpT, bp,
                                                   nullptr, nullptr, nullptr,
                                                   nullptr, out);
}